// Round 16
// baseline (152.434 us; speedup 1.0000x reference)
//
#include <hip/hip_runtime.h>
#include <hip/hip_bf16.h>

// Problem constants: B=4, T=4096, C=1024, H=16, D=64
#define BB 4
#define TT 4096
#define CC 1024
#define HH 16
#define DD 64

typedef __attribute__((ext_vector_type(8))) short short8;
typedef __attribute__((ext_vector_type(8))) __bf16 bf16x8;
typedef __attribute__((ext_vector_type(4))) float f32x4;

static __device__ __forceinline__ unsigned short f2bf(float f) {
    unsigned int u = __builtin_bit_cast(unsigned int, f);
    unsigned int r = (u + 0x7FFFu + ((u >> 16) & 1u)) >> 16;
    return (unsigned short)r;
}
static __device__ __forceinline__ float bf2f(unsigned short h) {
    return __builtin_bit_cast(float, ((unsigned int)h) << 16);
}
// 8 floats -> bf16x8 (RNE; compiler emits v_cvt_pk_bf16_f32)
static __device__ __forceinline__ bf16x8 cvt8(f32x4 a, f32x4 b) {
    bf16x8 r;
    r[0] = (__bf16)a[0]; r[1] = (__bf16)a[1]; r[2] = (__bf16)a[2]; r[3] = (__bf16)a[3];
    r[4] = (__bf16)b[0]; r[5] = (__bf16)b[1]; r[6] = (__bf16)b[2]; r[7] = (__bf16)b[3];
    return r;
}

// ---------------- fp32 -> bf16 conversion (W_attn only) ----------------
__global__ void k_f32_to_bf16(const float* __restrict__ src,
                              unsigned short* __restrict__ dst, int n4) {
    int i = blockIdx.x * 256 + threadIdx.x;
    if (i >= n4) return;
    float4 v = ((const float4*)src)[i];
    ushort4 o;
    o.x = f2bf(v.x); o.y = f2bf(v.y); o.z = f2bf(v.z); o.w = f2bf(v.w);
    ((ushort4*)dst)[i] = o;
}

// ============ 128x128 m97-style bf16 GEMM (4 waves, single-buffer) ============
// C[m,n] = sum_k A[m,k]*B[n,k] + bias[n];  B: NxK row-major bf16. BK=32.
// 4 waves (2M x 2N), per-wave output 64x64 (acc 4x4 f32x4). Single-buffered
// LDS, plain 2-barrier K-loop: {stage; __syncthreads; ds_read+MFMA;
// __syncthreads}. Small LDS (16/24KB) + modest VGPR -> 4-6 blocks/CU
// co-resident: other blocks' waves cover this block's barrier/staging stalls
// (the m97/m114 mechanism; deep in-block pipelines at 1 block/CU all hit the
// same ~30% MfmaUtil ceiling, rounds 12-14).
// MODE 0: A = fp32 (x) staged AS FP32 into LDS (16KB), cvt->bf16 at read.
//         C written bf16 + fused column sum-of-squares S.
// MODE 1: A = bf16 (8KB). C fp32 + bias. B PER-BATCH (Wp'): Bbase += b*N*K.
#define GBM 128
#define GBN 128
#define GBK 32

// bf16 128x32 tile (8KB): 512 chunks of 16B, 2/thread; row r slot j holds
// global k-chunk (j-(r>>1))&3  (inverse of read slot=(hi+(fr>>1))&3).
static __device__ __forceinline__ void stage_b16t(
    const unsigned short* __restrict__ Gbase, unsigned short* lbase,
    int k0, int K, int tid)
{
    #pragma unroll
    for (int q = 0; q < 2; ++q) {
        int c = q * 256 + tid;
        int r = c >> 2;
        int j = c & 3;
        int srcj = (j - (r >> 1)) & 3;
        const unsigned short* g = Gbase + (size_t)r * K + k0 + srcj * 8;
        __builtin_amdgcn_global_load_lds(
            (const __attribute__((address_space(1))) void*)g,
            (__attribute__((address_space(3))) void*)(lbase + c * 8), 16, 0, 0);
    }
}

// fp32 128x32 tile (16KB): 1024 chunks of 16B, 4/thread; row r slot j holds
// global 4-float chunk (j-r)&7  (inverse of read slot=(2hi+fr)&7).
static __device__ __forceinline__ void stage_a32t(
    const float* __restrict__ Gbase, unsigned short* lbase,
    int k0, int K, int tid)
{
    #pragma unroll
    for (int q = 0; q < 4; ++q) {
        int c = q * 256 + tid;
        int r = c >> 3;
        int j = c & 7;
        int srcj = (j - r) & 7;
        const float* g = Gbase + (size_t)r * K + k0 + srcj * 4;
        __builtin_amdgcn_global_load_lds(
            (const __attribute__((address_space(1))) void*)g,
            (__attribute__((address_space(3))) void*)(lbase + c * 8), 16, 0, 0);
    }
}

template<int MODE>
__global__ __launch_bounds__(256, 2)
void k_gemm128(const void* __restrict__ Asrc,
               const unsigned short* __restrict__ B,
               const float* __restrict__ bias,
               void* __restrict__ Cout,
               float* __restrict__ S,
               int M, int N, int K)
{
    // MODE0: A-fp32 8192 ushorts (16KB) + B 4096 (8KB) = 24KB
    // MODE1: A-bf16 4096 (8KB) + B 4096 (8KB) = 16KB
    constexpr int AREG = (MODE == 0) ? 8192 : 4096;   // B region start (ushort)
    __shared__ unsigned short lds[AREG + 4096];
    const int tid  = threadIdx.x;
    const int wave = tid >> 6;
    const int lane = tid & 63;
    const int wr = wave >> 1;   // 0..1
    const int wc = wave & 1;    // 0..1
    const int fr = lane & 15;
    const int hi = lane >> 4;   // 0..3

    // XCD-aware bijective swizzle (1024 blocks, 8 XCDs, chunk=128, bn fastest):
    // 8 consecutive swz share one A panel -> same-XCD L2 hit.
    const int wg  = blockIdx.x;
    const int swz = (wg & 7) * 128 + (wg >> 3);
    const int bn  = swz & 7;
    const int bm  = swz >> 3;   // 0..127
    const int b   = bm >> 5;    // batch (32 bm-tiles per batch)

    const float* Af32 = (const float*)Asrc + (size_t)(bm * GBM) * K;
    const unsigned short* Ab16 = (const unsigned short*)Asrc + (size_t)(bm * GBM) * K;
    const unsigned short* Bbase = B +
        ((size_t)((MODE == 1 ? b * N : 0) + bn * GBN)) * K;

    const int nt = K / GBK;   // 32

    // per-lane constant read offsets:
    const int slB  = (hi + (fr >> 1)) & 3;
    const int aoff = (wr * 64 + fr) * 32 + slB * 8;           // MODE1 A (+mi*512)
    const int boff = AREG + (wc * 64 + fr) * 32 + slB * 8;    // B (+ni*512)
    const int sl0  = (2 * hi + fr) & 7;                       // MODE0 fp32 slots
    const int sl1  = (2 * hi + 1 + fr) & 7;
    const int arowf = (wr * 64 + fr) * 32;                    // float idx (+mi*512)

    f32x4 acc[4][4] = {};

    for (int kt = 0; kt < nt; ++kt) {
        const int k0 = kt * GBK;
        if (MODE == 0) stage_a32t(Af32, lds, k0, K, tid);
        else           stage_b16t(Ab16, lds, k0, K, tid);
        stage_b16t(Bbase, lds + AREG, k0, K, tid);
        __syncthreads();   // drains vmcnt -> tiles visible

        bf16x8 af[4]; short8 bfr[4];
        #pragma unroll
        for (int i = 0; i < 4; ++i) bfr[i] = *(const short8*)&lds[boff + i * 512];
        if (MODE == 0) {
            const float* fbuf = (const float*)lds;
            #pragma unroll
            for (int mi = 0; mi < 4; ++mi)
                af[mi] = cvt8(*(const f32x4*)&fbuf[arowf + mi * 512 + sl0 * 4],
                              *(const f32x4*)&fbuf[arowf + mi * 512 + sl1 * 4]);
        } else {
            #pragma unroll
            for (int mi = 0; mi < 4; ++mi)
                af[mi] = __builtin_bit_cast(bf16x8, *(const short8*)&lds[aoff + mi * 512]);
        }

        #pragma unroll
        for (int mi = 0; mi < 4; ++mi)
            #pragma unroll
            for (int ni = 0; ni < 4; ++ni)
                acc[mi][ni] = __builtin_amdgcn_mfma_f32_16x16x32_bf16(
                    af[mi], __builtin_bit_cast(bf16x8, bfr[ni]),
                    acc[mi][ni], 0, 0, 0);
        __syncthreads();   // all waves done reading before next overwrite
    }

    // ---- epilogue: C/D layout col=lane&15, row=(lane>>4)*4+j ----
    const int cg = fr;
    const int rg = hi * 4;
    float* sblk = (float*)&lds[0];
    if (MODE == 0) {
        if (tid < GBN) sblk[tid] = 0.f;
        __syncthreads();
    }
    float csum[4] = {};
    #pragma unroll
    for (int mi = 0; mi < 4; ++mi) {
        #pragma unroll
        for (int ni = 0; ni < 4; ++ni) {
            int col = bn * GBN + wc * 64 + ni * 16 + cg;
            float bv = bias[col];
            #pragma unroll
            for (int j = 0; j < 4; ++j) {
                int row = bm * GBM + wr * 64 + mi * 16 + rg + j;
                float v = acc[mi][ni][j] + bv;
                if (MODE == 0) {
                    ((unsigned short*)Cout)[(size_t)row * N + col] = f2bf(v);
                    csum[ni] += v * v;
                } else {
                    ((float*)Cout)[(size_t)row * N + col] = v;
                }
            }
        }
    }
    if (MODE == 0) {
        #pragma unroll
        for (int ni = 0; ni < 4; ++ni)
            atomicAdd(&sblk[wc * 64 + ni * 16 + cg], csum[ni]);
        __syncthreads();
        if (tid < GBN) atomicAdd(&S[b * CC + bn * GBN + tid], sblk[tid]);
    }
}

// ------- per-row softmax over heads + IN-PLACE y = bf16(-(w*Pi)) -------
__global__ __launch_bounds__(256)
void k_row_softmax(unsigned short* __restrict__ w16, const float* __restrict__ S,
                   const float* __restrict__ temp,
                   float* __restrict__ dotsU, float* __restrict__ sumPi)
{
    __shared__ float dots_local[CC];
    __shared__ float sPi_local[HH];
    const int tid  = threadIdx.x;
    const int wave = tid >> 6;
    const int lane = tid & 63;
    const int bb   = blockIdx.x >> 7;
    const int tile = blockIdx.x & 127;

    for (int c = tid; c < CC; c += 256) dots_local[c] = 0.f;
    if (tid < HH) sPi_local[tid] = 0.f;
    __syncthreads();

    const int g3 = lane >> 3;
    const int li = lane & 7;

    float inv[2][8], tsc[2];
    #pragma unroll
    for (int q = 0; q < 2; ++q) {
        int c = q * 512 + lane * 8;
        const float4* sp = (const float4*)&S[bb * CC + c];
        float4 s0 = sp[0], s1 = sp[1];
        inv[q][0] = 1.f / fmaxf(s0.x, 1e-24f); inv[q][1] = 1.f / fmaxf(s0.y, 1e-24f);
        inv[q][2] = 1.f / fmaxf(s0.z, 1e-24f); inv[q][3] = 1.f / fmaxf(s0.w, 1e-24f);
        inv[q][4] = 1.f / fmaxf(s1.x, 1e-24f); inv[q][5] = 1.f / fmaxf(s1.y, 1e-24f);
        inv[q][6] = 1.f / fmaxf(s1.z, 1e-24f); inv[q][7] = 1.f / fmaxf(s1.w, 1e-24f);
        tsc[q] = temp[q * 8 + g3];
    }

    float dacc[2][8] = {};
    float sPiAcc[2] = {};

    for (int i = 0; i < 8; ++i) {
        int t = tile * 32 + wave * 8 + i;
        unsigned short* row = w16 + ((size_t)bb * TT + t) * CC;
        float wf[2][8];
        float pq[2];
        #pragma unroll
        for (int q = 0; q < 2; ++q) {
            short8 v = *(const short8*)&row[q * 512 + lane * 8];
            float s = 0.f;
            #pragma unroll
            for (int j = 0; j < 8; ++j) {
                wf[q][j] = bf2f((unsigned short)v[j]);
                s += wf[q][j] * wf[q][j] * inv[q][j];
            }
            pq[q] = s;
        }
        #pragma unroll
        for (int off = 1; off < 8; off <<= 1) {
            pq[0] += __shfl_xor(pq[0], off);
            pq[1] += __shfl_xor(pq[1], off);
        }
        pq[0] *= tsc[0]; pq[1] *= tsc[1];
        float mx = fmaxf(pq[0], pq[1]);
        mx = fmaxf(mx, __shfl_xor(mx, 8));
        mx = fmaxf(mx, __shfl_xor(mx, 16));
        mx = fmaxf(mx, __shfl_xor(mx, 32));
        float e0 = __expf(pq[0] - mx), e1 = __expf(pq[1] - mx);
        float ss = e0 + e1;
        ss += __shfl_xor(ss, 8);
        ss += __shfl_xor(ss, 16);
        ss += __shfl_xor(ss, 32);
        float rs = 1.f / ss;
        float piv[2] = { e0 * rs, e1 * rs };
        #pragma unroll
        for (int q = 0; q < 2; ++q) {
            short8 yo;
            #pragma unroll
            for (int j = 0; j < 8; ++j) {
                dacc[q][j] += piv[q] * wf[q][j] * wf[q][j];
                yo[j] = (short)f2bf(-wf[q][j] * piv[q]);
            }
            *(short8*)&row[q * 512 + lane * 8] = yo;   // in-place y = -(w*Pi)
            if (li == 0) sPiAcc[q] += piv[q];
        }
    }

    #pragma unroll
    for (int q = 0; q < 2; ++q) {
        int c = q * 512 + lane * 8;
        #pragma unroll
        for (int j = 0; j < 8; ++j)
            atomicAdd(&dots_local[c + j], dacc[q][j]);
        if (li == 0) atomicAdd(&sPi_local[q * 8 + g3], sPiAcc[q]);
    }
    __syncthreads();
    for (int c = tid; c < CC; c += 256) atomicAdd(&dotsU[bb * CC + c], dots_local[c]);
    if (tid < HH) atomicAdd(&sumPi[bb * HH + tid], sPi_local[tid]);
}

// -- Wp'[b,n,c] = bf16( Wp[n,c] * (+1/(1 + dotsU[b,c]/(sumPi[b,h]+1e-8))) ) --
// (sign: y already carries the minus)
__global__ void k_scale_wproj(const float* __restrict__ Wp,
                              const float* __restrict__ dotsU,
                              const float* __restrict__ sumPi,
                              unsigned short* __restrict__ out)
{
    int i = blockIdx.x * 256 + threadIdx.x;   // 1,048,576 groups of 4
    int bq  = i >> 18;                        // batch
    int rem = i & 262143;
    int n   = rem >> 8;
    int cg  = (rem & 255) * 4;
    float4 wv = *(const float4*)&Wp[n * CC + cg];
    float4 du = *(const float4*)&dotsU[bq * CC + cg];
    float sp = sumPi[bq * HH + (cg >> 6)] + 1e-8f;
    float a0 = 1.f / (1.f + du.x / sp);
    float a1 = 1.f / (1.f + du.y / sp);
    float a2 = 1.f / (1.f + du.z / sp);
    float a3 = 1.f / (1.f + du.w / sp);
    ushort4 o;
    o.x = f2bf(wv.x * a0); o.y = f2bf(wv.y * a1);
    o.z = f2bf(wv.z * a2); o.w = f2bf(wv.w * a3);
    *(ushort4*)&out[((size_t)bq * CC + n) * CC + cg] = o;
}

// ---------------- launch ----------------
extern "C" void kernel_launch(void* const* d_in, const int* in_sizes, int n_in,
                              void* d_out, int out_size, void* d_ws, size_t ws_size,
                              hipStream_t stream) {
    const float* x      = (const float*)d_in[0];
    const float* W_attn = (const float*)d_in[1];
    const float* b_attn = (const float*)d_in[2];
    const float* W_proj = (const float*)d_in[3];
    const float* b_proj = (const float*)d_in[4];
    const float* temp   = (const float*)d_in[5];

    char* ws = (char*)d_ws;
    unsigned short* w16   = (unsigned short*)(ws);             // 33554432 B (w, then y in-place)
    unsigned short* Wa16  = (unsigned short*)(ws + 33554432);  // 2097152 B
    unsigned short* Wp16b = (unsigned short*)(ws + 35651584);  // 8388608 B (per-batch Wp')
    float* S     = (float*)(ws + 44040192);  // 16384 B
    float* dotsU = (float*)(ws + 44056576);  // 16384 B
    float* sumPi = (float*)(ws + 44072960);  // 256 B

    // W_attn -> bf16 (x consumed as fp32 directly by GEMM1)
    k_f32_to_bf16<<<dim3(1024), dim3(256), 0, stream>>>(W_attn, Wa16, 262144);

    // zero accumulators (S, dotsU, sumPi contiguous)
    hipMemsetAsync(S, 0, 16384 + 16384 + 256, stream);

    // GEMM1: w16 = bf16(x @ Wa^T + b_attn); fused S[b,c] = sum_t w^2
    k_gemm128<0><<<dim3(1024), dim3(256), 0, stream>>>(
        x, Wa16, b_attn, w16, S, BB * TT, CC, CC);

    // head-softmax per token; in-place w16 <- bf16(-(w*Pi)); dotsU, sumPi
    k_row_softmax<<<dim3(512), dim3(256), 0, stream>>>(w16, S, temp, dotsU, sumPi);

    // per-batch projection weights with attn fold: Wp'[b] = attn ⊙ Wp
    k_scale_wproj<<<dim3(4096), dim3(256), 0, stream>>>(W_proj, dotsU, sumPi, Wp16b);

    // GEMM2: out = y @ Wp'[b]^T + b_proj
    k_gemm128<1><<<dim3(1024), dim3(256), 0, stream>>>(
        w16, Wp16b, b_proj, d_out, nullptr, BB * TT, CC, CC);
}

// Round 17
// 128.824 us; speedup vs baseline: 1.1833x; 1.1833x over previous
//
#include <hip/hip_runtime.h>
#include <hip/hip_bf16.h>

// Problem constants: B=4, T=4096, C=1024, H=16, D=64
#define BB 4
#define TT 4096
#define CC 1024
#define HH 16
#define DD 64

typedef __attribute__((ext_vector_type(8))) short short8;
typedef __attribute__((ext_vector_type(8))) __bf16 bf16x8;
typedef __attribute__((ext_vector_type(4))) float f32x4;

static __device__ __forceinline__ unsigned short f2bf(float f) {
    unsigned int u = __builtin_bit_cast(unsigned int, f);
    unsigned int r = (u + 0x7FFFu + ((u >> 16) & 1u)) >> 16;
    return (unsigned short)r;
}
static __device__ __forceinline__ float bf2f(unsigned short h) {
    return __builtin_bit_cast(float, ((unsigned int)h) << 16);
}
// 8 floats -> bf16x8 (RNE; compiler emits v_cvt_pk_bf16_f32)
static __device__ __forceinline__ bf16x8 cvt8(f32x4 a, f32x4 b) {
    bf16x8 r;
    r[0] = (__bf16)a[0]; r[1] = (__bf16)a[1]; r[2] = (__bf16)a[2]; r[3] = (__bf16)a[3];
    r[4] = (__bf16)b[0]; r[5] = (__bf16)b[1]; r[6] = (__bf16)b[2]; r[7] = (__bf16)b[3];
    return r;
}

// ---------------- fp32 -> bf16 conversion (W_attn only) ----------------
__global__ void k_f32_to_bf16(const float* __restrict__ src,
                              unsigned short* __restrict__ dst, int n4) {
    int i = blockIdx.x * 256 + threadIdx.x;
    if (i >= n4) return;
    float4 v = ((const float4*)src)[i];
    ushort4 o;
    o.x = f2bf(v.x); o.y = f2bf(v.y); o.z = f2bf(v.z); o.w = f2bf(v.w);
    ((ushort4*)dst)[i] = o;
}

// ---------------- shared staging helpers ----------------
// bf16 RxK32 tile: chunk c -> row r=c>>2, slot j=c&3 holds global k-chunk
// (j-(r>>1))&3  (inverse of read slot=(hi+(fr>>1))&3). 16B per chunk.
static __device__ __forceinline__ void stage_b16_512(
    const unsigned short* __restrict__ Gbase, unsigned short* lbase,
    int k0, int K, int wave, int lane)
{
    #pragma unroll
    for (int q = 0; q < 2; ++q) {
        int c = (wave * 2 + q) * 64 + lane;
        int r = c >> 2;
        int j = c & 3;
        int srcj = (j - (r >> 1)) & 3;
        const unsigned short* g = Gbase + (size_t)r * K + k0 + srcj * 8;
        __builtin_amdgcn_global_load_lds(
            (const __attribute__((address_space(1))) void*)g,
            (__attribute__((address_space(3))) void*)(lbase + (wave * 2 + q) * 512),
            16, 0, 0);
    }
}

// fp32 256x32 tile (32KB): 2048 chunks of 16B, 4/thread (512 threads);
// row r slot j holds global 4-float chunk (j-r)&7 (inverse of read (2hi+fr)&7).
static __device__ __forceinline__ void stage_a32_512(
    const float* __restrict__ Gbase, unsigned short* lbase,
    int k0, int K, int wave, int lane)
{
    #pragma unroll
    for (int q = 0; q < 4; ++q) {
        int c = q * 512 + wave * 64 + lane;
        int r = c >> 3;
        int j = c & 7;
        int srcj = (j - r) & 7;
        const float* g = Gbase + (size_t)r * K + k0 + srcj * 4;
        __builtin_amdgcn_global_load_lds(
            (const __attribute__((address_space(1))) void*)g,
            (__attribute__((address_space(3))) void*)(lbase + (q * 512 + wave * 64) * 8),
            16, 0, 0);
    }
}

// ========== GEMM1: 256x256, 3-slab, fp32-A (r15 proven, 60us) ==========
// w16[m,n] = bf16( sum_k x[m,k]*Wa[n,k] + b_attn[n] ); S[b,n] += w^2.
__global__ __launch_bounds__(512, 2)
void k_gemm1(const float* __restrict__ X,
             const unsigned short* __restrict__ B,
             const float* __restrict__ bias,
             unsigned short* __restrict__ Cout,
             float* __restrict__ S,
             int M, int N, int K)
{
    __shared__ unsigned short lds[3][24576];   // 3 x (A-fp32 32KB + B 16KB)
    const int tid  = threadIdx.x;
    const int wave = tid >> 6;
    const int lane = tid & 63;
    const int wr = wave >> 2, wc = wave & 3;
    const int fr = lane & 15, hi = lane >> 4;

    const int wg  = blockIdx.x;
    const int swz = (wg & 7) * 32 + (wg >> 3);
    const int bn  = swz & 3;
    const int bm  = swz >> 2;
    const int b   = bm >> 4;

    const float* Af32 = X + (size_t)(bm * 256) * K;
    const unsigned short* Bbase = B + (size_t)(bn * 256) * K;
    const int nt = K / 32;   // 32

    const int slB  = (hi + (fr >> 1)) & 3;
    const int boff = 16384 + (wc * 64 + fr) * 32 + slB * 8;
    const int sl0   = (2 * hi + fr) & 7;
    const int sl1   = (2 * hi + 1 + fr) & 7;
    const int arowf = (wr * 128 + fr) * 32;

    f32x4 acc[8][4] = {};

    stage_a32_512(Af32, lds[0],          0,  K, wave, lane);
    stage_b16_512(Bbase, lds[0] + 16384, 0,  K, wave, lane);
    stage_a32_512(Af32, lds[1],          32, K, wave, lane);
    stage_b16_512(Bbase, lds[1] + 16384, 32, K, wave, lane);

    int rb = 0;
    for (int kt = 0; kt < nt; ++kt) {
        const unsigned short* buf = lds[rb];
        unsigned short* sbuf = lds[(rb == 0) ? 2 : rb - 1];
        int ks = kt + 2; if (ks >= nt) ks = nt - 1;
        asm volatile("s_waitcnt vmcnt(6)" ::: "memory");
        __builtin_amdgcn_s_barrier();

        bf16x8 af[8]; short8 bfr[4];
        #pragma unroll
        for (int i = 0; i < 4; ++i) bfr[i] = *(const short8*)&buf[boff + i * 512];
        const float* fbuf = (const float*)buf;
        #pragma unroll
        for (int mi = 0; mi < 8; ++mi)
            af[mi] = cvt8(*(const f32x4*)&fbuf[arowf + mi * 512 + sl0 * 4],
                          *(const f32x4*)&fbuf[arowf + mi * 512 + sl1 * 4]);

        stage_a32_512(Af32, sbuf,          ks * 32, K, wave, lane);
        stage_b16_512(Bbase, sbuf + 16384, ks * 32, K, wave, lane);

        __builtin_amdgcn_s_setprio(1);
        #pragma unroll
        for (int mi = 0; mi < 8; ++mi)
            #pragma unroll
            for (int ni = 0; ni < 4; ++ni)
                acc[mi][ni] = __builtin_amdgcn_mfma_f32_16x16x32_bf16(
                    af[mi], __builtin_bit_cast(bf16x8, bfr[ni]),
                    acc[mi][ni], 0, 0, 0);
        __builtin_amdgcn_s_setprio(0);

        rb = (rb == 2) ? 0 : rb + 1;
    }

    __syncthreads();

    const int cg = fr;
    const int rg = hi * 4;
    float* sblk = (float*)&lds[0][0];
    if (tid < 256) sblk[tid] = 0.f;
    __syncthreads();
    float csum[4] = {};
    #pragma unroll
    for (int mi = 0; mi < 8; ++mi) {
        #pragma unroll
        for (int ni = 0; ni < 4; ++ni) {
            int col = bn * 256 + wc * 64 + ni * 16 + cg;
            float bv = bias[col];
            #pragma unroll
            for (int j = 0; j < 4; ++j) {
                int row = bm * 256 + wr * 128 + mi * 16 + rg + j;
                float v = acc[mi][ni][j] + bv;
                Cout[(size_t)row * N + col] = f2bf(v);
                csum[ni] += v * v;
            }
        }
    }
    #pragma unroll
    for (int ni = 0; ni < 4; ++ni)
        atomicAdd(&sblk[wc * 64 + ni * 16 + cg], csum[ni]);
    __syncthreads();
    if (tid < 256) atomicAdd(&S[b * CC + bn * 256 + tid], sblk[tid]);
}

// ========== GEMM2: 128x128 m97-style, bf16-A, per-batch B (r16 MODE1) ==========
// out[m,n] = sum_k y[m,k]*Wp'[b,n,k] + b_proj[n]  (fp32)
// bf16 128x32 tile (8KB), 2 chunks/thread at 256 threads.
static __device__ __forceinline__ void stage_b16_256(
    const unsigned short* __restrict__ Gbase, unsigned short* lbase,
    int k0, int K, int tid)
{
    #pragma unroll
    for (int q = 0; q < 2; ++q) {
        int c = q * 256 + tid;
        int r = c >> 2;
        int j = c & 3;
        int srcj = (j - (r >> 1)) & 3;
        const unsigned short* g = Gbase + (size_t)r * K + k0 + srcj * 8;
        __builtin_amdgcn_global_load_lds(
            (const __attribute__((address_space(1))) void*)g,
            (__attribute__((address_space(3))) void*)(lbase + c * 8), 16, 0, 0);
    }
}

__global__ __launch_bounds__(256, 2)
void k_gemm2(const unsigned short* __restrict__ A,
             const unsigned short* __restrict__ B,
             const float* __restrict__ bias,
             float* __restrict__ Cout,
             int M, int N, int K)
{
    __shared__ unsigned short lds[8192];   // A 8KB + B 8KB = 16KB
    const int tid  = threadIdx.x;
    const int wave = tid >> 6;
    const int lane = tid & 63;
    const int wr = wave >> 1, wc = wave & 1;
    const int fr = lane & 15, hi = lane >> 4;

    const int wg  = blockIdx.x;
    const int swz = (wg & 7) * 128 + (wg >> 3);
    const int bn  = swz & 7;
    const int bm  = swz >> 3;
    const int b   = bm >> 5;

    const unsigned short* Abase = A + (size_t)(bm * 128) * K;
    const unsigned short* Bbase = B + ((size_t)(b * N + bn * 128)) * K;
    const int nt = K / 32;

    const int slB  = (hi + (fr >> 1)) & 3;
    const int aoff = (wr * 64 + fr) * 32 + slB * 8;
    const int boff = 4096 + (wc * 64 + fr) * 32 + slB * 8;

    f32x4 acc[4][4] = {};

    for (int kt = 0; kt < nt; ++kt) {
        const int k0 = kt * 32;
        stage_b16_256(Abase, lds,        k0, K, tid);
        stage_b16_256(Bbase, lds + 4096, k0, K, tid);
        __syncthreads();

        bf16x8 af[4]; short8 bfr[4];
        #pragma unroll
        for (int i = 0; i < 4; ++i) bfr[i] = *(const short8*)&lds[boff + i * 512];
        #pragma unroll
        for (int mi = 0; mi < 4; ++mi)
            af[mi] = __builtin_bit_cast(bf16x8, *(const short8*)&lds[aoff + mi * 512]);

        #pragma unroll
        for (int mi = 0; mi < 4; ++mi)
            #pragma unroll
            for (int ni = 0; ni < 4; ++ni)
                acc[mi][ni] = __builtin_amdgcn_mfma_f32_16x16x32_bf16(
                    af[mi], __builtin_bit_cast(bf16x8, bfr[ni]),
                    acc[mi][ni], 0, 0, 0);
        __syncthreads();
    }

    const int cg = fr;
    const int rg = hi * 4;
    #pragma unroll
    for (int mi = 0; mi < 4; ++mi) {
        #pragma unroll
        for (int ni = 0; ni < 4; ++ni) {
            int col = bn * 128 + wc * 64 + ni * 16 + cg;
            float bv = bias[col];
            #pragma unroll
            for (int j = 0; j < 4; ++j) {
                int row = bm * 128 + wr * 64 + mi * 16 + rg + j;
                Cout[(size_t)row * N + col] = acc[mi][ni][j] + bv;
            }
        }
    }
}

// ------- per-row softmax over heads + IN-PLACE y = bf16(-(w*Pi)) -------
__global__ __launch_bounds__(256)
void k_row_softmax(unsigned short* __restrict__ w16, const float* __restrict__ S,
                   const float* __restrict__ temp,
                   float* __restrict__ dotsU, float* __restrict__ sumPi)
{
    __shared__ float dots_local[CC];
    __shared__ float sPi_local[HH];
    const int tid  = threadIdx.x;
    const int wave = tid >> 6;
    const int lane = tid & 63;
    const int bb   = blockIdx.x >> 7;
    const int tile = blockIdx.x & 127;

    for (int c = tid; c < CC; c += 256) dots_local[c] = 0.f;
    if (tid < HH) sPi_local[tid] = 0.f;
    __syncthreads();

    const int g3 = lane >> 3;
    const int li = lane & 7;

    float inv[2][8], tsc[2];
    #pragma unroll
    for (int q = 0; q < 2; ++q) {
        int c = q * 512 + lane * 8;
        const float4* sp = (const float4*)&S[bb * CC + c];
        float4 s0 = sp[0], s1 = sp[1];
        inv[q][0] = 1.f / fmaxf(s0.x, 1e-24f); inv[q][1] = 1.f / fmaxf(s0.y, 1e-24f);
        inv[q][2] = 1.f / fmaxf(s0.z, 1e-24f); inv[q][3] = 1.f / fmaxf(s0.w, 1e-24f);
        inv[q][4] = 1.f / fmaxf(s1.x, 1e-24f); inv[q][5] = 1.f / fmaxf(s1.y, 1e-24f);
        inv[q][6] = 1.f / fmaxf(s1.z, 1e-24f); inv[q][7] = 1.f / fmaxf(s1.w, 1e-24f);
        tsc[q] = temp[q * 8 + g3];
    }

    float dacc[2][8] = {};
    float sPiAcc[2] = {};

    for (int i = 0; i < 8; ++i) {
        int t = tile * 32 + wave * 8 + i;
        unsigned short* row = w16 + ((size_t)bb * TT + t) * CC;
        float wf[2][8];
        float pq[2];
        #pragma unroll
        for (int q = 0; q < 2; ++q) {
            short8 v = *(const short8*)&row[q * 512 + lane * 8];
            float s = 0.f;
            #pragma unroll
            for (int j = 0; j < 8; ++j) {
                wf[q][j] = bf2f((unsigned short)v[j]);
                s += wf[q][j] * wf[q][j] * inv[q][j];
            }
            pq[q] = s;
        }
        #pragma unroll
        for (int off = 1; off < 8; off <<= 1) {
            pq[0] += __shfl_xor(pq[0], off);
            pq[1] += __shfl_xor(pq[1], off);
        }
        pq[0] *= tsc[0]; pq[1] *= tsc[1];
        float mx = fmaxf(pq[0], pq[1]);
        mx = fmaxf(mx, __shfl_xor(mx, 8));
        mx = fmaxf(mx, __shfl_xor(mx, 16));
        mx = fmaxf(mx, __shfl_xor(mx, 32));
        float e0 = __expf(pq[0] - mx), e1 = __expf(pq[1] - mx);
        float ss = e0 + e1;
        ss += __shfl_xor(ss, 8);
        ss += __shfl_xor(ss, 16);
        ss += __shfl_xor(ss, 32);
        float rs = 1.f / ss;
        float piv[2] = { e0 * rs, e1 * rs };
        #pragma unroll
        for (int q = 0; q < 2; ++q) {
            short8 yo;
            #pragma unroll
            for (int j = 0; j < 8; ++j) {
                dacc[q][j] += piv[q] * wf[q][j] * wf[q][j];
                yo[j] = (short)f2bf(-wf[q][j] * piv[q]);
            }
            *(short8*)&row[q * 512 + lane * 8] = yo;   // in-place y = -(w*Pi)
            if (li == 0) sPiAcc[q] += piv[q];
        }
    }

    #pragma unroll
    for (int q = 0; q < 2; ++q) {
        int c = q * 512 + lane * 8;
        #pragma unroll
        for (int j = 0; j < 8; ++j)
            atomicAdd(&dots_local[c + j], dacc[q][j]);
        if (li == 0) atomicAdd(&sPi_local[q * 8 + g3], sPiAcc[q]);
    }
    __syncthreads();
    for (int c = tid; c < CC; c += 256) atomicAdd(&dotsU[bb * CC + c], dots_local[c]);
    if (tid < HH) atomicAdd(&sumPi[bb * HH + tid], sPi_local[tid]);
}

// -- Wp'[b,n,c] = bf16( Wp[n,c] * (+1/(1 + dotsU[b,c]/(sumPi[b,h]+1e-8))) ) --
__global__ void k_scale_wproj(const float* __restrict__ Wp,
                              const float* __restrict__ dotsU,
                              const float* __restrict__ sumPi,
                              unsigned short* __restrict__ out)
{
    int i = blockIdx.x * 256 + threadIdx.x;
    int bq  = i >> 18;
    int rem = i & 262143;
    int n   = rem >> 8;
    int cg  = (rem & 255) * 4;
    float4 wv = *(const float4*)&Wp[n * CC + cg];
    float4 du = *(const float4*)&dotsU[bq * CC + cg];
    float sp = sumPi[bq * HH + (cg >> 6)] + 1e-8f;
    float a0 = 1.f / (1.f + du.x / sp);
    float a1 = 1.f / (1.f + du.y / sp);
    float a2 = 1.f / (1.f + du.z / sp);
    float a3 = 1.f / (1.f + du.w / sp);
    ushort4 o;
    o.x = f2bf(wv.x * a0); o.y = f2bf(wv.y * a1);
    o.z = f2bf(wv.z * a2); o.w = f2bf(wv.w * a3);
    *(ushort4*)&out[((size_t)bq * CC + n) * CC + cg] = o;
}

// ---------------- launch ----------------
extern "C" void kernel_launch(void* const* d_in, const int* in_sizes, int n_in,
                              void* d_out, int out_size, void* d_ws, size_t ws_size,
                              hipStream_t stream) {
    const float* x      = (const float*)d_in[0];
    const float* W_attn = (const float*)d_in[1];
    const float* b_attn = (const float*)d_in[2];
    const float* W_proj = (const float*)d_in[3];
    const float* b_proj = (const float*)d_in[4];
    const float* temp   = (const float*)d_in[5];

    char* ws = (char*)d_ws;
    unsigned short* w16   = (unsigned short*)(ws);             // 32MB (w, then y in-place)
    unsigned short* Wa16  = (unsigned short*)(ws + 33554432);  // 2MB
    unsigned short* Wp16b = (unsigned short*)(ws + 35651584);  // 8MB (per-batch Wp')
    float* S     = (float*)(ws + 44040192);  // 16KB
    float* dotsU = (float*)(ws + 44056576);  // 16KB
    float* sumPi = (float*)(ws + 44072960);  // 256B

    // W_attn -> bf16 (x consumed as fp32 directly by GEMM1)
    k_f32_to_bf16<<<dim3(1024), dim3(256), 0, stream>>>(W_attn, Wa16, 262144);

    // zero accumulators
    hipMemsetAsync(S, 0, 16384 + 16384 + 256, stream);

    // GEMM1: w16 = bf16(x @ Wa^T + b_attn); fused S (r15 proven 3-slab fp32-A)
    k_gemm1<<<dim3(256), dim3(512), 0, stream>>>(
        x, Wa16, b_attn, w16, S, BB * TT, CC, CC);

    // head-softmax per token; in-place w16 <- bf16(-(w*Pi)); dotsU, sumPi
    k_row_softmax<<<dim3(512), dim3(256), 0, stream>>>(w16, S, temp, dotsU, sumPi);

    // per-batch projection weights with attn fold: Wp'[b] = attn ⊙ Wp
    k_scale_wproj<<<dim3(4096), dim3(256), 0, stream>>>(W_proj, dotsU, sumPi, Wp16b);

    // GEMM2: out = y @ Wp'[b]^T + b_proj (m97 128², high residency)
    k_gemm2<<<dim3(1024), dim3(256), 0, stream>>>(
        w16, Wp16b, b_proj, (float*)d_out, BB * TT, CC, CC);
}

// Round 18
// 122.527 us; speedup vs baseline: 1.2441x; 1.0514x over previous
//
#include <hip/hip_runtime.h>
#include <hip/hip_bf16.h>

// Problem constants: B=4, T=4096, C=1024, H=16, D=64
#define BB 4
#define TT 4096
#define CC 1024
#define HH 16
#define DD 64

typedef __attribute__((ext_vector_type(8))) short short8;
typedef __attribute__((ext_vector_type(8))) __bf16 bf16x8;
typedef __attribute__((ext_vector_type(4))) float f32x4;

static __device__ __forceinline__ unsigned short f2bf(float f) {
    unsigned int u = __builtin_bit_cast(unsigned int, f);
    unsigned int r = (u + 0x7FFFu + ((u >> 16) & 1u)) >> 16;
    return (unsigned short)r;
}
static __device__ __forceinline__ float bf2f(unsigned short h) {
    return __builtin_bit_cast(float, ((unsigned int)h) << 16);
}
// 8 floats -> bf16x8 (RNE; compiler emits v_cvt_pk_bf16_f32)
static __device__ __forceinline__ bf16x8 cvt8(f32x4 a, f32x4 b) {
    bf16x8 r;
    r[0] = (__bf16)a[0]; r[1] = (__bf16)a[1]; r[2] = (__bf16)a[2]; r[3] = (__bf16)a[3];
    r[4] = (__bf16)b[0]; r[5] = (__bf16)b[1]; r[6] = (__bf16)b[2]; r[7] = (__bf16)b[3];
    return r;
}

// ------- W_attn fp32->bf16 conversion + zero-init of S/dotsU/sumPi -------
__global__ void k_conv_and_zero(const float* __restrict__ src,
                                unsigned short* __restrict__ dst,
                                float* __restrict__ zbuf /* 8256 floats */) {
    int i = blockIdx.x * 256 + threadIdx.x;
    if (i < 262144) {
        float4 v = ((const float4*)src)[i];
        ushort4 o;
        o.x = f2bf(v.x); o.y = f2bf(v.y); o.z = f2bf(v.z); o.w = f2bf(v.w);
        ((ushort4*)dst)[i] = o;
    }
    if (i < 8256) zbuf[i] = 0.f;
}

// ================= 256x256 single-phase bf16 GEMM (r15 verbatim) =================
// C[m,n] = sum_k A[m,k]*B[n,k] + bias[n];  B: NxK row-major bf16.
// 8 waves (2M x 4N), per-wave output 128x64. BK=32.
// MODE 0: A = fp32 (x) staged AS FP32 into LDS, cvt->bf16 at fragment read.
//         3-slab rotation (48KB/slab), stage-2-ahead, vmcnt(6).
//         C written bf16 + fused column sum-of-squares S.
// MODE 1: A = bf16; 4-slab rotation, stage-3-ahead, vmcnt(8). C fp32.
//         B is PER-BATCH (Wp' holds attnScale fold): Bbase += b*N*K.
#define GBM 256
#define GBN 256
#define GBK 32

static __device__ __forceinline__ void stage_b16(
    const unsigned short* __restrict__ Gbase, unsigned short* lbase,
    int k0, int K, int wave, int lane)
{
    #pragma unroll
    for (int q = 0; q < 2; ++q) {
        int c = (wave * 2 + q) * 64 + lane;
        int r = c >> 2;
        int j = c & 3;
        int srcj = (j - (r >> 1)) & 3;
        const unsigned short* g = Gbase + (size_t)r * K + k0 + srcj * 8;
        __builtin_amdgcn_global_load_lds(
            (const __attribute__((address_space(1))) void*)g,
            (__attribute__((address_space(3))) void*)(lbase + (wave * 2 + q) * 512),
            16, 0, 0);
    }
}

static __device__ __forceinline__ void stage_a32(
    const float* __restrict__ Gbase, unsigned short* lbase,
    int k0, int K, int wave, int lane)
{
    #pragma unroll
    for (int q = 0; q < 4; ++q) {
        int c = q * 512 + wave * 64 + lane;
        int r = c >> 3;
        int j = c & 7;
        int srcj = (j - r) & 7;
        const float* g = Gbase + (size_t)r * K + k0 + srcj * 4;
        __builtin_amdgcn_global_load_lds(
            (const __attribute__((address_space(1))) void*)g,
            (__attribute__((address_space(3))) void*)(lbase + (q * 512 + wave * 64) * 8),
            16, 0, 0);
    }
}

template<int MODE>
__global__ __launch_bounds__(512, 2)
void k_gemm256(const void* __restrict__ Asrc,
               const unsigned short* __restrict__ B,
               const float* __restrict__ bias,
               void* __restrict__ Cout,
               float* __restrict__ S,
               int M, int N, int K)
{
    constexpr int NSLAB  = (MODE == 0) ? 3 : 4;
    constexpr int SLABSZ = (MODE == 0) ? 24576 : 16384;   // ushorts
    constexpr int BOFF0  = (MODE == 0) ? 16384 : 8192;    // B region start
    __shared__ unsigned short lds[NSLAB][SLABSZ];
    const int tid  = threadIdx.x;
    const int wave = tid >> 6;
    const int lane = tid & 63;
    const int wr = wave >> 2, wc = wave & 3;
    const int fr = lane & 15, hi = lane >> 4;

    const int wg  = blockIdx.x;
    const int swz = (wg & 7) * 32 + (wg >> 3);
    const int bn  = swz & 3;
    const int bm  = swz >> 2;
    const int b   = bm >> 4;

    const float* Af32 = (const float*)Asrc + (size_t)(bm * GBM) * K;
    const unsigned short* Ab16 = (const unsigned short*)Asrc + (size_t)(bm * GBM) * K;
    const unsigned short* Bbase = B +
        ((size_t)((MODE == 1 ? b * N : 0) + bn * GBN)) * K;

    const int nt = K / GBK;

    const int slB  = (hi + (fr >> 1)) & 3;
    const int aoff = (wr * 128 + fr) * 32 + slB * 8;
    const int boff = BOFF0 + (wc * 64 + fr) * 32 + slB * 8;
    const int sl0   = (2 * hi + fr) & 7;
    const int sl1   = (2 * hi + 1 + fr) & 7;
    const int arowf = (wr * 128 + fr) * 32;

    f32x4 acc[8][4] = {};

    if (MODE == 0) {
        stage_a32(Af32, lds[0],          0,   K, wave, lane);
        stage_b16(Bbase, lds[0] + BOFF0, 0,   K, wave, lane);
        stage_a32(Af32, lds[1],          GBK, K, wave, lane);
        stage_b16(Bbase, lds[1] + BOFF0, GBK, K, wave, lane);
    } else {
        stage_b16(Ab16, lds[0],          0,       K, wave, lane);
        stage_b16(Bbase, lds[0] + BOFF0, 0,       K, wave, lane);
        stage_b16(Ab16, lds[1],          GBK,     K, wave, lane);
        stage_b16(Bbase, lds[1] + BOFF0, GBK,     K, wave, lane);
        stage_b16(Ab16, lds[2],          2 * GBK, K, wave, lane);
        stage_b16(Bbase, lds[2] + BOFF0, 2 * GBK, K, wave, lane);
    }

    int rb = 0;
    for (int kt = 0; kt < nt; ++kt) {
        const unsigned short* buf;
        unsigned short* sbuf;
        int ks;
        if (MODE == 0) {
            buf  = lds[rb];
            sbuf = lds[(rb == 0) ? 2 : rb - 1];
            ks = kt + 2; if (ks >= nt) ks = nt - 1;
            asm volatile("s_waitcnt vmcnt(6)" ::: "memory");
        } else {
            buf  = lds[kt & 3];
            sbuf = lds[(kt + 3) & 3];
            ks = kt + 3; if (ks >= nt) ks = nt - 1;
            asm volatile("s_waitcnt vmcnt(8)" ::: "memory");
        }
        __builtin_amdgcn_s_barrier();

        bf16x8 af[8]; short8 bfr[4];
        #pragma unroll
        for (int i = 0; i < 4; ++i) bfr[i] = *(const short8*)&buf[boff + i * 512];
        if (MODE == 0) {
            const float* fbuf = (const float*)buf;
            #pragma unroll
            for (int mi = 0; mi < 8; ++mi)
                af[mi] = cvt8(*(const f32x4*)&fbuf[arowf + mi * 512 + sl0 * 4],
                              *(const f32x4*)&fbuf[arowf + mi * 512 + sl1 * 4]);
        } else {
            #pragma unroll
            for (int mi = 0; mi < 8; ++mi)
                af[mi] = __builtin_bit_cast(bf16x8, *(const short8*)&buf[aoff + mi * 512]);
        }

        if (MODE == 0) {
            stage_a32(Af32, sbuf,          ks * GBK, K, wave, lane);
            stage_b16(Bbase, sbuf + BOFF0, ks * GBK, K, wave, lane);
        } else {
            stage_b16(Ab16, sbuf,          ks * GBK, K, wave, lane);
            stage_b16(Bbase, sbuf + BOFF0, ks * GBK, K, wave, lane);
        }

        __builtin_amdgcn_s_setprio(1);
        #pragma unroll
        for (int mi = 0; mi < 8; ++mi)
            #pragma unroll
            for (int ni = 0; ni < 4; ++ni)
                acc[mi][ni] = __builtin_amdgcn_mfma_f32_16x16x32_bf16(
                    af[mi], __builtin_bit_cast(bf16x8, bfr[ni]),
                    acc[mi][ni], 0, 0, 0);
        __builtin_amdgcn_s_setprio(0);

        rb = (rb == (NSLAB - 1)) ? 0 : rb + 1;
    }

    __syncthreads();

    const int cg = fr;
    const int rg = hi * 4;
    float* sblk = (float*)&lds[0][0];
    if (MODE == 0) {
        if (tid < GBN) sblk[tid] = 0.f;
        __syncthreads();
    }
    float csum[4] = {};
    #pragma unroll
    for (int mi = 0; mi < 8; ++mi) {
        #pragma unroll
        for (int ni = 0; ni < 4; ++ni) {
            int col = bn * GBN + wc * 64 + ni * 16 + cg;
            float bv = bias[col];
            #pragma unroll
            for (int j = 0; j < 4; ++j) {
                int row = bm * GBM + wr * 128 + mi * 16 + rg + j;
                float v = acc[mi][ni][j] + bv;
                if (MODE == 0) {
                    ((unsigned short*)Cout)[(size_t)row * N + col] = f2bf(v);
                    csum[ni] += v * v;
                } else {
                    ((float*)Cout)[(size_t)row * N + col] = v;
                }
            }
        }
    }
    if (MODE == 0) {
        #pragma unroll
        for (int ni = 0; ni < 4; ++ni)
            atomicAdd(&sblk[wc * 64 + ni * 16 + cg], csum[ni]);
        __syncthreads();
        if (tid < GBN) atomicAdd(&S[b * CC + bn * GBN + tid], sblk[tid]);
    }
}

// ------- per-row softmax over heads + IN-PLACE y = bf16(-(w*Pi)) -------
__global__ __launch_bounds__(256)
void k_row_softmax(unsigned short* __restrict__ w16, const float* __restrict__ S,
                   const float* __restrict__ temp,
                   float* __restrict__ dotsU, float* __restrict__ sumPi)
{
    __shared__ float dots_local[CC];
    __shared__ float sPi_local[HH];
    const int tid  = threadIdx.x;
    const int wave = tid >> 6;
    const int lane = tid & 63;
    const int bb   = blockIdx.x >> 7;
    const int tile = blockIdx.x & 127;

    for (int c = tid; c < CC; c += 256) dots_local[c] = 0.f;
    if (tid < HH) sPi_local[tid] = 0.f;
    __syncthreads();

    const int g3 = lane >> 3;
    const int li = lane & 7;

    float inv[2][8], tsc[2];
    #pragma unroll
    for (int q = 0; q < 2; ++q) {
        int c = q * 512 + lane * 8;
        const float4* sp = (const float4*)&S[bb * CC + c];
        float4 s0 = sp[0], s1 = sp[1];
        inv[q][0] = 1.f / fmaxf(s0.x, 1e-24f); inv[q][1] = 1.f / fmaxf(s0.y, 1e-24f);
        inv[q][2] = 1.f / fmaxf(s0.z, 1e-24f); inv[q][3] = 1.f / fmaxf(s0.w, 1e-24f);
        inv[q][4] = 1.f / fmaxf(s1.x, 1e-24f); inv[q][5] = 1.f / fmaxf(s1.y, 1e-24f);
        inv[q][6] = 1.f / fmaxf(s1.z, 1e-24f); inv[q][7] = 1.f / fmaxf(s1.w, 1e-24f);
        tsc[q] = temp[q * 8 + g3];
    }

    float dacc[2][8] = {};
    float sPiAcc[2] = {};

    for (int i = 0; i < 8; ++i) {
        int t = tile * 32 + wave * 8 + i;
        unsigned short* row = w16 + ((size_t)bb * TT + t) * CC;
        float wf[2][8];
        float pq[2];
        #pragma unroll
        for (int q = 0; q < 2; ++q) {
            short8 v = *(const short8*)&row[q * 512 + lane * 8];
            float s = 0.f;
            #pragma unroll
            for (int j = 0; j < 8; ++j) {
                wf[q][j] = bf2f((unsigned short)v[j]);
                s += wf[q][j] * wf[q][j] * inv[q][j];
            }
            pq[q] = s;
        }
        #pragma unroll
        for (int off = 1; off < 8; off <<= 1) {
            pq[0] += __shfl_xor(pq[0], off);
            pq[1] += __shfl_xor(pq[1], off);
        }
        pq[0] *= tsc[0]; pq[1] *= tsc[1];
        float mx = fmaxf(pq[0], pq[1]);
        mx = fmaxf(mx, __shfl_xor(mx, 8));
        mx = fmaxf(mx, __shfl_xor(mx, 16));
        mx = fmaxf(mx, __shfl_xor(mx, 32));
        float e0 = __expf(pq[0] - mx), e1 = __expf(pq[1] - mx);
        float ss = e0 + e1;
        ss += __shfl_xor(ss, 8);
        ss += __shfl_xor(ss, 16);
        ss += __shfl_xor(ss, 32);
        float rs = 1.f / ss;
        float piv[2] = { e0 * rs, e1 * rs };
        #pragma unroll
        for (int q = 0; q < 2; ++q) {
            short8 yo;
            #pragma unroll
            for (int j = 0; j < 8; ++j) {
                dacc[q][j] += piv[q] * wf[q][j] * wf[q][j];
                yo[j] = (short)f2bf(-wf[q][j] * piv[q]);
            }
            *(short8*)&row[q * 512 + lane * 8] = yo;   // in-place y = -(w*Pi)
            if (li == 0) sPiAcc[q] += piv[q];
        }
    }

    #pragma unroll
    for (int q = 0; q < 2; ++q) {
        int c = q * 512 + lane * 8;
        #pragma unroll
        for (int j = 0; j < 8; ++j)
            atomicAdd(&dots_local[c + j], dacc[q][j]);
        if (li == 0) atomicAdd(&sPi_local[q * 8 + g3], sPiAcc[q]);
    }
    __syncthreads();
    for (int c = tid; c < CC; c += 256) atomicAdd(&dotsU[bb * CC + c], dots_local[c]);
    if (tid < HH) atomicAdd(&sumPi[bb * HH + tid], sPi_local[tid]);
}

// -- Wp'[b,n,c] = bf16( Wp[n,c] * (+1/(1 + dotsU[b,c]/(sumPi[b,h]+1e-8))) ) --
// (sign: y already carries the minus)
__global__ void k_scale_wproj(const float* __restrict__ Wp,
                              const float* __restrict__ dotsU,
                              const float* __restrict__ sumPi,
                              unsigned short* __restrict__ out)
{
    int i = blockIdx.x * 256 + threadIdx.x;
    int bq  = i >> 18;
    int rem = i & 262143;
    int n   = rem >> 8;
    int cg  = (rem & 255) * 4;
    float4 wv = *(const float4*)&Wp[n * CC + cg];
    float4 du = *(const float4*)&dotsU[bq * CC + cg];
    float sp = sumPi[bq * HH + (cg >> 6)] + 1e-8f;
    float a0 = 1.f / (1.f + du.x / sp);
    float a1 = 1.f / (1.f + du.y / sp);
    float a2 = 1.f / (1.f + du.z / sp);
    float a3 = 1.f / (1.f + du.w / sp);
    ushort4 o;
    o.x = f2bf(wv.x * a0); o.y = f2bf(wv.y * a1);
    o.z = f2bf(wv.z * a2); o.w = f2bf(wv.w * a3);
    *(ushort4*)&out[((size_t)bq * CC + n) * CC + cg] = o;
}

// ---------------- launch ----------------
extern "C" void kernel_launch(void* const* d_in, const int* in_sizes, int n_in,
                              void* d_out, int out_size, void* d_ws, size_t ws_size,
                              hipStream_t stream) {
    const float* x      = (const float*)d_in[0];
    const float* W_attn = (const float*)d_in[1];
    const float* b_attn = (const float*)d_in[2];
    const float* W_proj = (const float*)d_in[3];
    const float* b_proj = (const float*)d_in[4];
    const float* temp   = (const float*)d_in[5];

    char* ws = (char*)d_ws;
    unsigned short* w16   = (unsigned short*)(ws);             // 32MB (w, then y in-place)
    unsigned short* Wa16  = (unsigned short*)(ws + 33554432);  // 2MB
    unsigned short* Wp16b = (unsigned short*)(ws + 35651584);  // 8MB (per-batch Wp')
    float* S     = (float*)(ws + 44040192);  // 16KB
    float* dotsU = (float*)(ws + 44056576);  // 16KB
    float* sumPi = (float*)(ws + 44072960);  // 256B
    // S, dotsU, sumPi are contiguous: 4096 + 4096 + 64 = 8256 floats

    // W_attn -> bf16, fused with zero-init of S/dotsU/sumPi (one dispatch)
    k_conv_and_zero<<<dim3(1024), dim3(256), 0, stream>>>(W_attn, Wa16, S);

    // GEMM1: w16 = bf16(x @ Wa^T + b_attn); fused S[b,c] = sum_t w^2
    k_gemm256<0><<<dim3(256), dim3(512), 0, stream>>>(
        x, Wa16, b_attn, w16, S, BB * TT, CC, CC);

    // head-softmax per token; in-place w16 <- bf16(-(w*Pi)); dotsU, sumPi
    k_row_softmax<<<dim3(512), dim3(256), 0, stream>>>(w16, S, temp, dotsU, sumPi);

    // per-batch projection weights with attn fold: Wp'[b] = attn ⊙ Wp
    k_scale_wproj<<<dim3(4096), dim3(256), 0, stream>>>(W_proj, dotsU, sumPi, Wp16b);

    // GEMM2: out = y @ Wp'[b]^T + b_proj
    k_gemm256<1><<<dim3(256), dim3(512), 0, stream>>>(
        w16, Wp16b, b_proj, d_out, nullptr, BB * TT, CC, CC);
}